// Round 20
// baseline (116.179 us; speedup 1.0000x reference)
//
#include <hip/hip_runtime.h>
#include <hip/hip_bf16.h>
#include <hip/hip_fp16.h>
#include <stdint.h>

#define K_DIM 4096
#define N_DIM 11008
#define M_DIM 512
#define PK_ROW 5504          // int32 code-words per k-row (one per n-pair)
#define SC_ROW 172           // scale blocks per k-row

typedef __attribute__((ext_vector_type(4))) float f32x4;
typedef __attribute__((ext_vector_type(4))) int i32x4;
typedef __attribute__((ext_vector_type(4))) unsigned int u32x4;
typedef __attribute__((ext_vector_type(8))) _Float16 half8;
typedef __attribute__((ext_vector_type(8))) short bf16x8;

__constant__ float NF4[16] = {
    -1.0f, -0.6961928009986877f, -0.5250730514526367f, -0.39491748809814453f,
    -0.28444138169288635f, -0.18477343022823334f, -0.09105003625154495f, 0.0f,
    0.07958029955625534f, 0.16093020141124725f, 0.24611230194568634f,
    0.33791524171829224f, 0.44070982933044434f, 0.5626170039176941f,
    0.7229568362236023f, 1.0f};

union H8 { u32x4 v; half8 h; };

__device__ __forceinline__ unsigned h2mul(unsigned a, unsigned b) {
  union { __half2 h; unsigned u; } x, y, r;
  x.u = a; y.u = b;
  r.h = x.h * y.h;           // v_pk_mul_f16
  return r.u;
}
__device__ __forceinline__ unsigned hpack(float a, float b) {
  union { __half2 h; unsigned u; } c;
  c.h = __floats2half2_rn(a, b);
  return c.u;
}
__device__ __forceinline__ unsigned f2bf(float v) {  // for fallback kernel
  union { __hip_bfloat16 h; unsigned short u; } cv;
  cv.h = __float2bfloat16(v);
  return (unsigned)cv.u;
}

// ---- merged pre-pass: codes transpose + A conv + scales pack ----
__global__ __launch_bounds__(256) void prep_all(
    const float* __restrict__ x, const int* __restrict__ packed,
    const float* __restrict__ scales, unsigned* __restrict__ wsa,
    unsigned* __restrict__ codes, unsigned* __restrict__ scalesp) {
  const int bid = blockIdx.x;
  const int t = threadIdx.x;
  if (bid < 5504) {
    // codes: out dword D = ((n>>4)*512 + (kp>>2))*16 + (n&15);
    // byte (n,kp) = code(2kp,n)<<4 | code(2kp+1,n)
    const int kt = bid & 63;
    const int nt = bid >> 6;
    __shared__ unsigned char Sb[128 * 36];
    const int npl = t & 63;
    const int kq = t >> 6;
    const int np = nt * 64 + npl;
#pragma unroll
    for (int i = 0; i < 8; ++i) {
      const int kpl = kq + i * 4;
      const int k = kt * 64 + kpl * 2;
      const int w0 = packed[(size_t)k * PK_ROW + np];
      const int w1 = packed[(size_t)(k + 1) * PK_ROW + np];
      Sb[(npl * 2) * 36 + kpl] =
          (unsigned char)((((w0 >> 4) & 15) << 4) | ((w1 >> 4) & 15));
      Sb[(npl * 2 + 1) * 36 + kpl] =
          (unsigned char)(((w0 & 15) << 4) | (w1 & 15));
    }
    __syncthreads();
#pragma unroll
    for (int i = 0; i < 4; ++i) {
      const int lin = t + 256 * i;
      const int n16 = lin & 15;
      const int kp4l = (lin >> 4) & 7;
      const int nb16l = lin >> 7;
      const unsigned v = *(const unsigned*)(Sb + (nb16l * 16 + n16) * 36 + kp4l * 4);
      const size_t D = ((size_t)(nt * 8 + nb16l) * 512 + kt * 8 + kp4l) * 16 + n16;
      codes[D] = v;
    }
  } else if (bid < 6528) {
    // conv_a: unit (m16,k32)=1KB; lane l holds A[m16*16+(l&15)][k32*32+(l>>4)*8..+8)
    const int wid = (bid - 5504) * 4 + (t >> 6);
    const int lane = t & 63;
    const int m16 = wid >> 7, k32 = wid & 127;
    const int m = m16 * 16 + (lane & 15);
    const int k = k32 * 32 + (lane >> 4) * 8;
    const float* src = x + (size_t)m * K_DIM + k;
    f32x4 v0 = *(const f32x4*)src;
    f32x4 v1 = *(const f32x4*)(src + 4);
    u32x4 d;
    d[0] = hpack(v0[0], v0[1]);
    d[1] = hpack(v0[2], v0[3]);
    d[2] = hpack(v1[0], v1[1]);
    d[3] = hpack(v1[2], v1[3]);
    *(u32x4*)(wsa + (size_t)wid * 256 + lane * 4) = d;
  } else {
    const int g = (bid - 6528) * 256 + t;
    if (g < SC_ROW * 2048) {
      const int kp = g / SC_ROW;
      const int nb = g - kp * SC_ROW;
      const float s0 = scales[(size_t)(2 * kp) * SC_ROW + nb];
      const float s1 = scales[(size_t)(2 * kp + 1) * SC_ROW + nb];
      scalesp[(size_t)nb * 2048 + kp] = hpack(s0, s1);
    }
  }
}

// ---- main: fused NF4 GEMM, f16 MFMA, nm=8 wave, 4-way in-block K-split ----
// R20: R18 chassis (16-copy LUT + dense Otile stores: the ONLY config with
// WRITE=1x/FETCH=30MB — R16/17/19's 32-copy in-block variants all showed the
// 5x write anomaly) + the dequant-economics lever: wave tile 128m x 64n
// (nm=8, acc[8][4]) -> 16 gathers + 16 pk_mul per 32 MFMA (0.5/MFMA, halved).
// A traffic invariant at 688MB (wn=64). Block = 4 waves = 4 k-quarters of one
// 128x64 tile; in-block reduction serialized (kh1 w, kh2 +=, kh3 +=, kh0
// +=bias) per 32-row round. Grid 688 = XCD n-slice x (n_loc x 4 m).
__global__ __launch_bounds__(256, 2) void nf4_gemm_ib8(
    const unsigned* __restrict__ codes, const unsigned* __restrict__ scalesp,
    const unsigned* __restrict__ wsa, const float* __restrict__ bias,
    float* __restrict__ out) {
  __shared__ unsigned LutR[256 * 16];             // 16-copy LUT (16KB)
  __shared__ __align__(16) float Otile[32][68];   // 8.7KB, pad 68

  const int bid = blockIdx.x;          // 704 = 8 XCD * 88 (16 idle)
  const int x = bid & 7;
  const int local = bid >> 3;          // 0..87
  const int S = (x < 4) ? x * 22 : 88 + (x - 4) * 21;  // XCD n-slice (of 64)
  const int cnt = (x < 4) ? 22 : 21;   // 172 = 4*22 + 4*21
  if (local >= cnt * 4) return;        // block-uniform early exit
  const int n_tile = (S + (local >> 2)) * 64;
  const int m_tile = (local & 3) * 128;

  const int t = threadIdx.x;
  {  // replicated LUT: dword idx = byte*16 + copy; lane uses copy=lane&15
    const int c = t & 15;
    const int b0 = t >> 4;             // 0..15
#pragma unroll
    for (int i = 0; i < 16; ++i) {
      const int b = b0 + 16 * i;
      LutR[b * 16 + c] = hpack(NF4[(b >> 4) & 15], NF4[b & 15]);
    }
  }
  __syncthreads();  // LUT visible

  const int lane = t & 63;
  const int kh = t >> 6;               // wave id == k-quarter
  const int l15 = lane & 15;
  const int kslice = lane >> 4;
  const int lb = lane & 15;            // LUT copy index
  const int m16w = m_tile >> 4;
  const int nf0 = n_tile >> 4;
  const int nb64 = n_tile >> 6;

  unsigned cb[4];
#pragma unroll
  for (int j = 0; j < 4; ++j) cb[j] = (unsigned)(nf0 + j) * 8192 + lane;
  const unsigned sb = (unsigned)nb64 * 2048 + kslice * 4;
  unsigned ab[8];
#pragma unroll
  for (int fm = 0; fm < 8; ++fm)
    ab[fm] = (unsigned)(m16w + fm) * 32768 + lane * 4;

  f32x4 acc[8][4];
#pragma unroll
  for (int i = 0; i < 8; ++i)
#pragma unroll
    for (int j = 0; j < 4; ++j) acc[i][j] = (f32x4){0.f, 0.f, 0.f, 0.f};

  const int NS = 32;                   // K/4 per k-quarter, 32 k per step
  const int s_base = kh * NS;

  auto LOAD = [&](int sl, unsigned* c, u32x4& sv, u32x4* A) {
    const unsigned s = (unsigned)(s_base + sl);
#pragma unroll
    for (int j = 0; j < 4; ++j) c[j] = codes[cb[j] + 64u * s];
    sv = *(const u32x4*)(scalesp + sb + 16u * s);
#pragma unroll
    for (int fm = 0; fm < 8; ++fm)
      A[fm] = *(const u32x4*)(wsa + ab[fm] + 256u * s);
  };
  auto STEP = [&](const unsigned* c, const u32x4& sv, const u32x4* A) {
#pragma unroll
    for (int j = 0; j < 4; ++j) {
      const unsigned cw = c[j];
      H8 B;
      B.v[0] = h2mul(LutR[((cw & 255u) << 4) | lb], sv[0]);
      B.v[1] = h2mul(LutR[(((cw >> 8) & 255u) << 4) | lb], sv[1]);
      B.v[2] = h2mul(LutR[(((cw >> 16) & 255u) << 4) | lb], sv[2]);
      B.v[3] = h2mul(LutR[((cw >> 24) << 4) | lb], sv[3]);
#pragma unroll
      for (int fm = 0; fm < 8; ++fm) {
        H8 a; a.v = A[fm];
        acc[fm][j] = __builtin_amdgcn_mfma_f32_16x16x32_f16(a.h, B.h, acc[fm][j], 0, 0, 0);
      }
    }
  };

  unsigned Xc[4], Yc[4];
  u32x4 Xs, Ys;
  u32x4 XA[8], YA[8];
  LOAD(0, Xc, Xs, XA);
#pragma unroll 1
  for (int s = 0; s < NS; s += 2) {
    LOAD(s + 1, Yc, Ys, YA);           // s+1 <= NS-1 always
    STEP(Xc, Xs, XA);
    if (s + 2 < NS) LOAD(s + 2, Xc, Xs, XA);
    STEP(Yc, Ys, YA);
  }

  // ---- epilogue: 4 rounds of 32 rows (fm-pairs); serialized k-reduction
  // into Otile, then dense f32x4 streaming (256B/row = 2 full 128B lines) ----
#pragma unroll 1
  for (int p = 0; p < 4; ++p) {
    if (kh == 1) {
#pragma unroll
      for (int j = 0; j < 4; ++j)
#pragma unroll
        for (int f = 0; f < 2; ++f)
#pragma unroll
          for (int r = 0; r < 4; ++r)
            Otile[f * 16 + kslice * 4 + r][j * 16 + l15] = acc[2 * p + f][j][r];
    }
    __syncthreads();
    if (kh == 2) {
#pragma unroll
      for (int j = 0; j < 4; ++j)
#pragma unroll
        for (int f = 0; f < 2; ++f)
#pragma unroll
          for (int r = 0; r < 4; ++r)
            Otile[f * 16 + kslice * 4 + r][j * 16 + l15] += acc[2 * p + f][j][r];
    }
    __syncthreads();
    if (kh == 3) {
#pragma unroll
      for (int j = 0; j < 4; ++j)
#pragma unroll
        for (int f = 0; f < 2; ++f)
#pragma unroll
          for (int r = 0; r < 4; ++r)
            Otile[f * 16 + kslice * 4 + r][j * 16 + l15] += acc[2 * p + f][j][r];
    }
    __syncthreads();
    if (kh == 0) {
#pragma unroll
      for (int j = 0; j < 4; ++j) {
        const float bi = bias[n_tile + j * 16 + l15];
#pragma unroll
        for (int f = 0; f < 2; ++f)
#pragma unroll
          for (int r = 0; r < 4; ++r)
            Otile[f * 16 + kslice * 4 + r][j * 16 + l15] +=
                acc[2 * p + f][j][r] + bi;
      }
    }
    __syncthreads();
    // stream 32 rows: all 4 waves; per instr 64 lanes = 4 rows x 16 x 16B
    {
      const int c4v = lane & 15;       // 16 cols of f32x4 (64 floats)
      const int r4 = lane >> 4;        // row within quad
#pragma unroll
      for (int it = 0; it < 2; ++it) {
        const int row = it * 16 + kh * 4 + r4;
        const f32x4 v = *(const f32x4*)&Otile[row][c4v * 4];
        *(f32x4*)&out[(size_t)(m_tile + p * 32 + row) * N_DIM + n_tile + c4v * 4] = v;
      }
    }
    __syncthreads();
  }
}

// ---- fallback (round-1 kernel, proven 155us): used only if ws tiny ----
#define FLDS 72
__global__ __launch_bounds__(256) void nf4_gemm_fused(
    const float* __restrict__ x, const int* __restrict__ packed,
    const float* __restrict__ scales, const float* __restrict__ bias,
    float* __restrict__ out) {
  __shared__ unsigned short AldsF[128 * FLDS];
  __shared__ unsigned short BldsF[128 * FLDS];
  __shared__ float2 Lut[256];
  const int t = threadIdx.x;
  const int bid = blockIdx.x;
  const int swz = (bid & 7) * 43 + (bid >> 3);
  const int m_tile = (swz / 86) * 128;
  const int n_tile = (swz % 86) * 128;
  Lut[t] = make_float2(NF4[(t >> 4) & 15], NF4[t & 15]);
  const int lane = t & 63;
  const int wid = t >> 6;
  const int wm = (wid >> 1) * 64;
  const int wn = (wid & 1) * 64;
  const int l15 = lane & 15;
  const int l4 = lane >> 4;
  f32x4 acc[4][4];
#pragma unroll
  for (int i = 0; i < 4; ++i)
#pragma unroll
    for (int j = 0; j < 4; ++j) acc[i][j] = (f32x4){0.f, 0.f, 0.f, 0.f};
  const int mlane = t & 15;
  const int n_sub = mlane * 8;
  const int k_sub = 4 * (((t >> 4) + mlane) & 15);
  const int c4 = t & 15;
  const int r0 = t >> 4;
  for (int k0 = 0; k0 < K_DIM; k0 += 64) {
    __syncthreads();
#pragma unroll
    for (int i = 0; i < 8; ++i) {
      const int row = r0 + 16 * i;
      f32x4 xv = *(const f32x4*)(x + (size_t)(m_tile + row) * K_DIM + k0 + c4 * 4);
      uint2 d;
      d.x = f2bf(xv[0]) | (f2bf(xv[1]) << 16);
      d.y = f2bf(xv[2]) | (f2bf(xv[3]) << 16);
      *(uint2*)(&AldsF[row * FLDS + c4 * 4]) = d;
    }
    {
      const int* pk = packed + (size_t)(k0 + k_sub) * PK_ROW + ((n_tile + n_sub) >> 1);
      i32x4 w[4];
      float s[4];
#pragma unroll
      for (int kk = 0; kk < 4; ++kk) {
        w[kk] = *(const i32x4*)(pk + (size_t)kk * PK_ROW);
        s[kk] = scales[(size_t)(k0 + k_sub + kk) * SC_ROW + ((n_tile + n_sub) >> 6)];
      }
      float v[4][8];
#pragma unroll
      for (int kk = 0; kk < 4; ++kk)
#pragma unroll
        for (int e = 0; e < 4; ++e) {
          const int b = w[kk][e] & 0xFF;
          const float2 p = Lut[b];
          v[kk][2 * e] = p.x * s[kk];
          v[kk][2 * e + 1] = p.y * s[kk];
        }
#pragma unroll
      for (int j = 0; j < 8; ++j) {
        uint2 d;
        d.x = f2bf(v[0][j]) | (f2bf(v[1][j]) << 16);
        d.y = f2bf(v[2][j]) | (f2bf(v[3][j]) << 16);
        *(uint2*)(&BldsF[(n_sub + j) * FLDS + k_sub]) = d;
      }
    }
    __syncthreads();
#pragma unroll
    for (int ks = 0; ks < 2; ++ks) {
      bf16x8 af[4], bfv[4];
#pragma unroll
      for (int fm = 0; fm < 4; ++fm)
        af[fm] = *(const bf16x8*)(&AldsF[(wm + fm * 16 + l15) * FLDS + ks * 32 + l4 * 8]);
#pragma unroll
      for (int fn = 0; fn < 4; ++fn)
        bfv[fn] = *(const bf16x8*)(&BldsF[(wn + fn * 16 + l15) * FLDS + ks * 32 + l4 * 8]);
#pragma unroll
      for (int fm = 0; fm < 4; ++fm)
#pragma unroll
        for (int fn = 0; fn < 4; ++fn)
          acc[fm][fn] = __builtin_amdgcn_mfma_f32_16x16x32_bf16(af[fm], bfv[fn], acc[fm][fn], 0, 0, 0);
    }
  }
#pragma unroll
  for (int fn = 0; fn < 4; ++fn) {
    const float bi = bias[n_tile + wn + fn * 16 + l15];
#pragma unroll
    for (int fm = 0; fm < 4; ++fm)
#pragma unroll
      for (int r = 0; r < 4; ++r) {
        const int gr = m_tile + wm + fm * 16 + l4 * 4 + r;
        out[(size_t)gr * N_DIM + n_tile + wn + fn * 16 + l15] = acc[fm][fn][r] + bi;
      }
  }
}

extern "C" void kernel_launch(void* const* d_in, const int* in_sizes, int n_in,
                              void* d_out, int out_size, void* d_ws, size_t ws_size,
                              hipStream_t stream) {
  const float* x = (const float*)d_in[0];
  const int* packed = (const int*)d_in[1];
  const float* scales = (const float*)d_in[2];
  const float* bias = (const float*)d_in[3];
  float* out = (float*)d_out;

  const size_t A_BYTES = (size_t)M_DIM * K_DIM * 2;            // 4,194,304
  const size_t C_BYTES = (size_t)688 * 512 * 16 * 4;           // 22,544,384
  const size_t S_BYTES = (size_t)SC_ROW * 2048 * 4;            // 1,409,024
  const size_t need = A_BYTES + C_BYTES + S_BYTES;             // 28.1 MB

  if (ws_size >= need) {
    unsigned* wsa = (unsigned*)d_ws;
    unsigned* codes = (unsigned*)((char*)d_ws + A_BYTES);
    unsigned* scalesp = (unsigned*)((char*)d_ws + A_BYTES + C_BYTES);
    prep_all<<<dim3(7904), dim3(256), 0, stream>>>(x, packed, scales, wsa, codes, scalesp);
    nf4_gemm_ib8<<<dim3(704), dim3(256), 0, stream>>>(codes, scalesp, wsa, bias, out);
  } else {
    nf4_gemm_fused<<<dim3(344), dim3(256), 0, stream>>>(x, packed, scales, bias, out);
  }
}

// Round 21
// 83.044 us; speedup vs baseline: 1.3990x; 1.3990x over previous
//
#include <hip/hip_runtime.h>
#include <hip/hip_bf16.h>
#include <hip/hip_fp16.h>
#include <stdint.h>

#define K_DIM 4096
#define N_DIM 11008
#define M_DIM 512
#define PK_ROW 5504          // int32 code-words per k-row (one per n-pair)
#define SC_ROW 172           // scale blocks per k-row

typedef __attribute__((ext_vector_type(4))) float f32x4;
typedef __attribute__((ext_vector_type(4))) int i32x4;
typedef __attribute__((ext_vector_type(4))) unsigned int u32x4;
typedef __attribute__((ext_vector_type(8))) _Float16 half8;
typedef __attribute__((ext_vector_type(8))) short bf16x8;

__constant__ float NF4[16] = {
    -1.0f, -0.6961928009986877f, -0.5250730514526367f, -0.39491748809814453f,
    -0.28444138169288635f, -0.18477343022823334f, -0.09105003625154495f, 0.0f,
    0.07958029955625534f, 0.16093020141124725f, 0.24611230194568634f,
    0.33791524171829224f, 0.44070982933044434f, 0.5626170039176941f,
    0.7229568362236023f, 1.0f};

union H8 { u32x4 v; half8 h; };

__device__ __forceinline__ unsigned h2mul(unsigned a, unsigned b) {
  union { __half2 h; unsigned u; } x, y, r;
  x.u = a; y.u = b;
  r.h = x.h * y.h;           // v_pk_mul_f16
  return r.u;
}
__device__ __forceinline__ unsigned hpack(float a, float b) {
  union { __half2 h; unsigned u; } c;
  c.h = __floats2half2_rn(a, b);
  return c.u;
}
__device__ __forceinline__ unsigned f2bf(float v) {  // for fallback kernel
  union { __hip_bfloat16 h; unsigned short u; } cv;
  cv.h = __float2bfloat16(v);
  return (unsigned)cv.u;
}

// ---- merged pre-pass: codes transpose + A conv + scales pack ----
__global__ __launch_bounds__(256) void prep_all(
    const float* __restrict__ x, const int* __restrict__ packed,
    const float* __restrict__ scales, unsigned* __restrict__ wsa,
    unsigned* __restrict__ codes, unsigned* __restrict__ scalesp) {
  const int bid = blockIdx.x;
  const int t = threadIdx.x;
  if (bid < 5504) {
    // codes: out dword D = ((n>>4)*512 + (kp>>2))*16 + (n&15);
    // byte (n,kp) = code(2kp,n)<<4 | code(2kp+1,n)
    const int kt = bid & 63;
    const int nt = bid >> 6;
    __shared__ unsigned char Sb[128 * 36];
    const int npl = t & 63;
    const int kq = t >> 6;
    const int np = nt * 64 + npl;
#pragma unroll
    for (int i = 0; i < 8; ++i) {
      const int kpl = kq + i * 4;
      const int k = kt * 64 + kpl * 2;
      const int w0 = packed[(size_t)k * PK_ROW + np];
      const int w1 = packed[(size_t)(k + 1) * PK_ROW + np];
      Sb[(npl * 2) * 36 + kpl] =
          (unsigned char)((((w0 >> 4) & 15) << 4) | ((w1 >> 4) & 15));
      Sb[(npl * 2 + 1) * 36 + kpl] =
          (unsigned char)(((w0 & 15) << 4) | (w1 & 15));
    }
    __syncthreads();
#pragma unroll
    for (int i = 0; i < 4; ++i) {
      const int lin = t + 256 * i;
      const int n16 = lin & 15;
      const int kp4l = (lin >> 4) & 7;
      const int nb16l = lin >> 7;
      const unsigned v = *(const unsigned*)(Sb + (nb16l * 16 + n16) * 36 + kp4l * 4);
      const size_t D = ((size_t)(nt * 8 + nb16l) * 512 + kt * 8 + kp4l) * 16 + n16;
      codes[D] = v;
    }
  } else if (bid < 6528) {
    // conv_a: unit (m16,k32)=1KB; lane l holds A[m16*16+(l&15)][k32*32+(l>>4)*8..+8)
    const int wid = (bid - 5504) * 4 + (t >> 6);
    const int lane = t & 63;
    const int m16 = wid >> 7, k32 = wid & 127;
    const int m = m16 * 16 + (lane & 15);
    const int k = k32 * 32 + (lane >> 4) * 8;
    const float* src = x + (size_t)m * K_DIM + k;
    f32x4 v0 = *(const f32x4*)src;
    f32x4 v1 = *(const f32x4*)(src + 4);
    u32x4 d;
    d[0] = hpack(v0[0], v0[1]);
    d[1] = hpack(v0[2], v0[3]);
    d[2] = hpack(v1[0], v1[1]);
    d[3] = hpack(v1[2], v1[3]);
    *(u32x4*)(wsa + (size_t)wid * 256 + lane * 4) = d;
  } else {
    const int g = (bid - 6528) * 256 + t;
    if (g < SC_ROW * 2048) {
      const int kp = g / SC_ROW;
      const int nb = g - kp * SC_ROW;
      const float s0 = scales[(size_t)(2 * kp) * SC_ROW + nb];
      const float s1 = scales[(size_t)(2 * kp + 1) * SC_ROW + nb];
      scalesp[(size_t)nb * 2048 + kp] = hpack(s0, s1);
    }
  }
}

// ---- main: fused NF4 GEMM, f16 MFMA, in-block K-reduction ----
// FINAL (= R18, measured best: 83.2us total, GEMM 64us). Key proven elements:
// - compact codes (22.5MB) + XCD n-slice map -> FETCH 30MB (codes L2-resident)
// - in-block 2-way K-split reduction -> no reduce pass, no partial traffic
// - dense f32x4 stores via LDS out-tile -> WRITE 22MB (=output; scalar dword
//   stores had inflated it to 110MB via partial-line flushes = +15us)
// - 16-copy replicated LUT (5.6e6 conflict-cycles ~2-4us; the 32-copy variant
//   paradoxically re-triggered the write anomaly in R19 - do not "fix")
// Core loop: per-wave 64x64, 2-deep named prefetch; 8 experiments (TLP x3,
// ILP x2, restructure x3) confirmed its gather->mul->MFMA chain is the
// invariant ~64us bound for this structure.
__global__ __launch_bounds__(256, 3) void nf4_gemm_ib(
    const unsigned* __restrict__ codes, const unsigned* __restrict__ scalesp,
    const unsigned* __restrict__ wsa, const float* __restrict__ bias,
    float* __restrict__ out) {
  __shared__ unsigned LutR[256 * 16];       // 16-copy replicated LUT (16KB)
  __shared__ __align__(16) float Otile[64][132];  // 33.8KB, pad 132

  const int bid = blockIdx.x;          // 704 = 8 XCD * 88 (16 idle)
  const int x = bid & 7;
  const int local = bid >> 3;          // 0..87
  const int S = (x < 6) ? x * 11 : 66 + (x - 6) * 10;  // XCD n-partition
  const int cnt = (x < 6) ? 11 : 10;   // 86 = 6*11 + 2*10
  if (local >= cnt * 8) return;        // block-uniform early exit
  const int n_tile = (S + (local >> 3)) * 128;
  const int m_tile = (local & 7) * 64;

  const int t = threadIdx.x;
  {  // replicated LUT: dword idx = byte*16 + copy; lane uses copy=lane&15
    const int c = t & 15;
    const int b0 = t >> 4;             // 0..15
#pragma unroll
    for (int i = 0; i < 16; ++i) {
      const int b = b0 + 16 * i;
      LutR[b * 16 + c] = hpack(NF4[(b >> 4) & 15], NF4[b & 15]);
    }
  }
  __syncthreads();  // LUT visible

  const int lane = t & 63;
  const int wid = t >> 6;              // 0..3
  const int kh = wid >> 1;             // k-half
  const int nh = wid & 1;              // n-half (64 cols)
  const int l15 = lane & 15;
  const int kslice = lane >> 4;
  const int lb = lane & 15;            // LUT copy index
  const int m16w = m_tile >> 4;        // wave covers the block's full 64 m
  const int nf0 = (n_tile >> 4) + nh * 4;
  const int nb64 = (n_tile >> 6) + nh;

  unsigned cb[4];
#pragma unroll
  for (int j = 0; j < 4; ++j) cb[j] = (unsigned)(nf0 + j) * 8192 + lane;
  const unsigned sb = (unsigned)nb64 * 2048 + kslice * 4;
  unsigned ab[4];
#pragma unroll
  for (int fm = 0; fm < 4; ++fm)
    ab[fm] = (unsigned)(m16w + fm) * 32768 + lane * 4;

  f32x4 acc[4][4];
#pragma unroll
  for (int i = 0; i < 4; ++i)
#pragma unroll
    for (int j = 0; j < 4; ++j) acc[i][j] = (f32x4){0.f, 0.f, 0.f, 0.f};

  const int NS = 64;                   // K/2 per k-half, 32 k per step
  const int s_base = kh * NS;

  auto LOAD = [&](int sl, unsigned* c, u32x4& sv, u32x4* A) {
    const unsigned s = (unsigned)(s_base + sl);
#pragma unroll
    for (int j = 0; j < 4; ++j) c[j] = codes[cb[j] + 64u * s];
    sv = *(const u32x4*)(scalesp + sb + 16u * s);
#pragma unroll
    for (int fm = 0; fm < 4; ++fm)
      A[fm] = *(const u32x4*)(wsa + ab[fm] + 256u * s);
  };
  auto STEP = [&](const unsigned* c, const u32x4& sv, const u32x4* A) {
    H8 a[4];
#pragma unroll
    for (int fm = 0; fm < 4; ++fm) a[fm].v = A[fm];
#pragma unroll
    for (int j = 0; j < 4; ++j) {
      const unsigned cw = c[j];
      H8 B;
      B.v[0] = h2mul(LutR[((cw & 255u) << 4) | lb], sv[0]);
      B.v[1] = h2mul(LutR[(((cw >> 8) & 255u) << 4) | lb], sv[1]);
      B.v[2] = h2mul(LutR[(((cw >> 16) & 255u) << 4) | lb], sv[2]);
      B.v[3] = h2mul(LutR[((cw >> 24) << 4) | lb], sv[3]);
#pragma unroll
      for (int fm = 0; fm < 4; ++fm)
        acc[fm][j] = __builtin_amdgcn_mfma_f32_16x16x32_f16(a[fm].h, B.h, acc[fm][j], 0, 0, 0);
    }
  };

  unsigned Xc[4], Yc[4];
  u32x4 Xs, Ys;
  u32x4 XA[4], YA[4];
  LOAD(0, Xc, Xs, XA);
#pragma unroll 1
  for (int s = 0; s < NS; s += 2) {
    LOAD(s + 1, Yc, Ys, YA);           // s+1 <= NS-1 always
    STEP(Xc, Xs, XA);
    if (s + 2 < NS) LOAD(s + 2, Xc, Xs, XA);
    STEP(Yc, Ys, YA);
  }

  // ---- epilogue: reduce into LDS out-tile, then dense f32x4 streaming ----
  if (kh == 1) {
#pragma unroll
    for (int j = 0; j < 4; ++j)
#pragma unroll
      for (int fm = 0; fm < 4; ++fm)
#pragma unroll
        for (int r = 0; r < 4; ++r)
          Otile[fm * 16 + kslice * 4 + r][nh * 64 + j * 16 + l15] = acc[fm][j][r];
  }
  __syncthreads();
  if (kh == 0) {
#pragma unroll
    for (int j = 0; j < 4; ++j) {
      const float bi = bias[n_tile + nh * 64 + j * 16 + l15];
#pragma unroll
      for (int fm = 0; fm < 4; ++fm)
#pragma unroll
        for (int r = 0; r < 4; ++r) {
          const int row = fm * 16 + kslice * 4 + r;
          const int col = nh * 64 + j * 16 + l15;
          Otile[row][col] += acc[fm][j][r] + bi;
        }
    }
  }
  __syncthreads();
  // stream: all 4 waves; per instr 64 lanes = 2 rows x 32 lanes x 16B
  // (512B contiguous per row = 4 full 128B lines).
  {
    const int c8 = lane & 31;          // 32 cols of f32x4
    const int r2 = lane >> 5;          // row within pair
#pragma unroll
    for (int it = 0; it < 8; ++it) {
      const int row = it * 8 + wid * 2 + r2;
      const f32x4 v = *(const f32x4*)&Otile[row][c8 * 4];
      *(f32x4*)&out[(size_t)(m_tile + row) * N_DIM + n_tile + c8 * 4] = v;
    }
  }
}

// ---- fallback (round-1 kernel, proven 155us): used only if ws tiny ----
#define FLDS 72
__global__ __launch_bounds__(256) void nf4_gemm_fused(
    const float* __restrict__ x, const int* __restrict__ packed,
    const float* __restrict__ scales, const float* __restrict__ bias,
    float* __restrict__ out) {
  __shared__ unsigned short AldsF[128 * FLDS];
  __shared__ unsigned short BldsF[128 * FLDS];
  __shared__ float2 Lut[256];
  const int t = threadIdx.x;
  const int bid = blockIdx.x;
  const int swz = (bid & 7) * 43 + (bid >> 3);
  const int m_tile = (swz / 86) * 128;
  const int n_tile = (swz % 86) * 128;
  Lut[t] = make_float2(NF4[(t >> 4) & 15], NF4[t & 15]);
  const int lane = t & 63;
  const int wid = t >> 6;
  const int wm = (wid >> 1) * 64;
  const int wn = (wid & 1) * 64;
  const int l15 = lane & 15;
  const int l4 = lane >> 4;
  f32x4 acc[4][4];
#pragma unroll
  for (int i = 0; i < 4; ++i)
#pragma unroll
    for (int j = 0; j < 4; ++j) acc[i][j] = (f32x4){0.f, 0.f, 0.f, 0.f};
  const int mlane = t & 15;
  const int n_sub = mlane * 8;
  const int k_sub = 4 * (((t >> 4) + mlane) & 15);
  const int c4 = t & 15;
  const int r0 = t >> 4;
  for (int k0 = 0; k0 < K_DIM; k0 += 64) {
    __syncthreads();
#pragma unroll
    for (int i = 0; i < 8; ++i) {
      const int row = r0 + 16 * i;
      f32x4 xv = *(const f32x4*)(x + (size_t)(m_tile + row) * K_DIM + k0 + c4 * 4);
      uint2 d;
      d.x = f2bf(xv[0]) | (f2bf(xv[1]) << 16);
      d.y = f2bf(xv[2]) | (f2bf(xv[3]) << 16);
      *(uint2*)(&AldsF[row * FLDS + c4 * 4]) = d;
    }
    {
      const int* pk = packed + (size_t)(k0 + k_sub) * PK_ROW + ((n_tile + n_sub) >> 1);
      i32x4 w[4];
      float s[4];
#pragma unroll
      for (int kk = 0; kk < 4; ++kk) {
        w[kk] = *(const i32x4*)(pk + (size_t)kk * PK_ROW);
        s[kk] = scales[(size_t)(k0 + k_sub + kk) * SC_ROW + ((n_tile + n_sub) >> 6)];
      }
      float v[4][8];
#pragma unroll
      for (int kk = 0; kk < 4; ++kk)
#pragma unroll
        for (int e = 0; e < 4; ++e) {
          const int b = w[kk][e] & 0xFF;
          const float2 p = Lut[b];
          v[kk][2 * e] = p.x * s[kk];
          v[kk][2 * e + 1] = p.y * s[kk];
        }
#pragma unroll
      for (int j = 0; j < 8; ++j) {
        uint2 d;
        d.x = f2bf(v[0][j]) | (f2bf(v[1][j]) << 16);
        d.y = f2bf(v[2][j]) | (f2bf(v[3][j]) << 16);
        *(uint2*)(&BldsF[(n_sub + j) * FLDS + k_sub]) = d;
      }
    }
    __syncthreads();
#pragma unroll
    for (int ks = 0; ks < 2; ++ks) {
      bf16x8 af[4], bfv[4];
#pragma unroll
      for (int fm = 0; fm < 4; ++fm)
        af[fm] = *(const bf16x8*)(&AldsF[(wm + fm * 16 + l15) * FLDS + ks * 32 + l4 * 8]);
#pragma unroll
      for (int fn = 0; fn < 4; ++fn)
        bfv[fn] = *(const bf16x8*)(&BldsF[(wn + fn * 16 + l15) * FLDS + ks * 32 + l4 * 8]);
#pragma unroll
      for (int fm = 0; fm < 4; ++fm)
#pragma unroll
        for (int fn = 0; fn < 4; ++fn)
          acc[fm][fn] = __builtin_amdgcn_mfma_f32_16x16x32_bf16(af[fm], bfv[fn], acc[fm][fn], 0, 0, 0);
    }
  }
#pragma unroll
  for (int fn = 0; fn < 4; ++fn) {
    const float bi = bias[n_tile + wn + fn * 16 + l15];
#pragma unroll
    for (int fm = 0; fm < 4; ++fm)
#pragma unroll
      for (int r = 0; r < 4; ++r) {
        const int gr = m_tile + wm + fm * 16 + l4 * 4 + r;
        out[(size_t)gr * N_DIM + n_tile + wn + fn * 16 + l15] = acc[fm][fn][r] + bi;
      }
  }
}

extern "C" void kernel_launch(void* const* d_in, const int* in_sizes, int n_in,
                              void* d_out, int out_size, void* d_ws, size_t ws_size,
                              hipStream_t stream) {
  const float* x = (const float*)d_in[0];
  const int* packed = (const int*)d_in[1];
  const float* scales = (const float*)d_in[2];
  const float* bias = (const float*)d_in[3];
  float* out = (float*)d_out;

  const size_t A_BYTES = (size_t)M_DIM * K_DIM * 2;            // 4,194,304
  const size_t C_BYTES = (size_t)688 * 512 * 16 * 4;           // 22,544,384
  const size_t S_BYTES = (size_t)SC_ROW * 2048 * 4;            // 1,409,024
  const size_t need = A_BYTES + C_BYTES + S_BYTES;             // 28.1 MB

  if (ws_size >= need) {
    unsigned* wsa = (unsigned*)d_ws;
    unsigned* codes = (unsigned*)((char*)d_ws + A_BYTES);
    unsigned* scalesp = (unsigned*)((char*)d_ws + A_BYTES + C_BYTES);
    prep_all<<<dim3(7904), dim3(256), 0, stream>>>(x, packed, scales, wsa, codes, scalesp);
    nf4_gemm_ib<<<dim3(704), dim3(256), 0, stream>>>(codes, scalesp, wsa, bias, out);
  } else {
    nf4_gemm_fused<<<dim3(344), dim3(256), 0, stream>>>(x, packed, scales, bias, out);
  }
}